// Round 11
// baseline (5890.521 us; speedup 1.0000x reference)
//
#include <hip/hip_runtime.h>
#include <hip/hip_bf16.h>

// ---------------- constants ----------------
// B=32, N=8192, S1=512, S2=256, K=32
#define NB 32
#define NP 8192

// ---------- distance helpers (match numpy: no FMA contraction) ----------
__device__ __forceinline__ float dist3(float ax, float ay, float az,
                                       float bx, float by, float bz) {
#pragma clang fp contract(off)
  float dx = ax - bx, dy = ay - by, dz = az - bz;
  return dx * dx + dy * dy + dz * dz;
}
__device__ __forceinline__ float sumsq3(float x, float y, float z) {
#pragma clang fp contract(off)
  return x * x + y * y + z * z;
}
__device__ __forceinline__ float knndist(float qx, float qy, float qz, float qq,
                                         float cx, float cy, float cz) {
#pragma clang fp contract(off)
  float dot = qx * cx + qy * cy + qz * cz;
  float cc = cx * cx + cy * cy + cz * cz;
  return (qq - 2.0f * dot) + cc;
}

// ---------------- weight transpose: wT[d][O] = w[o][d] ----------------
__global__ void k_transpose(const float* __restrict__ w, float* __restrict__ wT,
                            int O, int Dd) {
  int i = blockIdx.x * 256 + threadIdx.x;
  if (i < O * Dd) {
    int o = i / Dd, d = i - o * Dd;
    wT[d * O + o] = w[i];
  }
}

// ---------------- WdT[d][o] = w[o][D+d] - w[o][d]  (d < D, split correction) -------
__global__ void k_wdiff(const float* __restrict__ w, float* __restrict__ WdT,
                        int O, int D) {
  int i = blockIdx.x * 256 + threadIdx.x;
  if (i < D * O) {
    int d = i / O, o = i - d * O;
    WdT[i] = w[o * 2 * D + D + d] - w[o * 2 * D + d];
  }
}

// ---------------- stage1a: xyz + y1 = x * w1^T ----------------
__global__ __launch_bounds__(256) void k_s1a(const float* __restrict__ x,
                                             const float* __restrict__ w1,
                                             float* __restrict__ xyz,
                                             float* __restrict__ y1) {
  __shared__ float w1s[192];
  int t = threadIdx.x;
  if (t < 192) w1s[t] = w1[t];
  int gid = blockIdx.x * 256 + t;  // 0 .. B*N-1
  int b = gid >> 13, n = gid & (NP - 1);
  __syncthreads();
  const size_t xb = (size_t)b * 3 * NP;
  float x0 = x[xb + n], x1 = x[xb + NP + n], x2 = x[xb + 2 * NP + n];
  xyz[(size_t)gid * 3 + 0] = x0;
  xyz[(size_t)gid * 3 + 1] = x1;
  xyz[(size_t)gid * 3 + 2] = x2;
  float* yo = y1 + (size_t)gid * 64;
#pragma unroll
  for (int o = 0; o < 64; o += 4) {
    float4 v;
    v.x = x0 * w1s[(o + 0) * 3] + x1 * w1s[(o + 0) * 3 + 1] + x2 * w1s[(o + 0) * 3 + 2];
    v.y = x0 * w1s[(o + 1) * 3] + x1 * w1s[(o + 1) * 3 + 1] + x2 * w1s[(o + 1) * 3 + 2];
    v.z = x0 * w1s[(o + 2) * 3] + x1 * w1s[(o + 2) * 3 + 1] + x2 * w1s[(o + 2) * 3 + 2];
    v.w = x0 * w1s[(o + 3) * 3] + x1 * w1s[(o + 3) * 3 + 1] + x2 * w1s[(o + 3) * 3 + 2];
    *(float4*)&yo[o] = v;
  }
}

// ---------------- per-channel (C=64) sum/sumsq over [M][64], float4 ----------------
__global__ __launch_bounds__(256) void k_colstats(const float* __restrict__ buf,
                                                  size_t ME4, float* __restrict__ part) {
  __shared__ float red[128];
  int t = threadIdx.x;
  if (t < 128) red[t] = 0.f;
  float s[4] = {0.f, 0.f, 0.f, 0.f}, q[4] = {0.f, 0.f, 0.f, 0.f};
  size_t stride = (size_t)gridDim.x * 256;
  size_t i0 = (size_t)blockIdx.x * 256 + t;
  int c0 = (int)((i0 * 4) & 63);
  for (size_t i = i0; i < ME4; i += stride) {
    float4 v = ((const float4*)buf)[i];
    s[0] += v.x; q[0] += v.x * v.x;
    s[1] += v.y; q[1] += v.y * v.y;
    s[2] += v.z; q[2] += v.z * v.z;
    s[3] += v.w; q[3] += v.w * v.w;
  }
  __syncthreads();
#pragma unroll
  for (int j = 0; j < 4; ++j) {
    atomicAdd(&red[c0 + j], s[j]);
    atomicAdd(&red[64 + c0 + j], q[j]);
  }
  __syncthreads();
  if (t < 128) atomicAdd(&part[(size_t)(blockIdx.x & 63) * 128 + t], red[t]);
}

// ---------------- BN finalize: partials[P][2*C] -> scale/shift[2*C] ----------------
__global__ void k_bnfinal(const float* __restrict__ part, const float* __restrict__ gamma,
                          const float* __restrict__ beta, float invcnt, int C, int P,
                          float* __restrict__ sc) {
  int c = threadIdx.x;
  if (c >= C) return;
  float s = 0.f, q = 0.f;
  for (int p = 0; p < P; ++p) {
    s += part[(size_t)p * 2 * C + c];
    q += part[(size_t)p * 2 * C + C + c];
  }
  float mean = s * invcnt;
  float var = fmaxf(q * invcnt - mean * mean, 0.f);
  float scale = gamma[c] * rsqrtf(var + 1e-5f);
  sc[c] = scale;
  sc[C + c] = beta[c] - mean * scale;
}

// ---------------- stage1c: y2 = w2 * relu(bn(y1)), 64-point tiles (in-place safe) ----
__global__ __launch_bounds__(256) void k_s1c(const float* __restrict__ y1,
                                             const float* __restrict__ w2T,
                                             const float* __restrict__ sc1,
                                             float* __restrict__ y2) {
  __shared__ __align__(16) float f1[64 * 65];
  __shared__ __align__(16) float w2s[64 * 64];
  __shared__ float scs[128];
  int t = threadIdx.x;
  if (t < 128) scs[t] = sc1[t];
  for (int i = t; i < 4096; i += 256) w2s[i] = w2T[i];
  size_t base = (size_t)blockIdx.x * 4096;
  __syncthreads();
  for (int i = t; i < 4096; i += 256) {
    int p = i >> 6, c = i & 63;
    float v = y1[base + i];
    v = fmaxf(0.f, v * scs[c] + scs[64 + c]);
    f1[p * 65 + c] = v;
  }
  __syncthreads();
  int pq = t & 15, oq = t >> 4;
  int p0 = pq * 4, o0 = oq * 4;
  float ac[4][4] = {};
  for (int c = 0; c < 64; ++c) {
    float4 wv = *(const float4*)&w2s[c * 64 + o0];
    float a0 = f1[(p0 + 0) * 65 + c];
    float a1 = f1[(p0 + 1) * 65 + c];
    float a2 = f1[(p0 + 2) * 65 + c];
    float a3 = f1[(p0 + 3) * 65 + c];
    ac[0][0] += a0 * wv.x; ac[0][1] += a0 * wv.y; ac[0][2] += a0 * wv.z; ac[0][3] += a0 * wv.w;
    ac[1][0] += a1 * wv.x; ac[1][1] += a1 * wv.y; ac[1][2] += a1 * wv.z; ac[1][3] += a1 * wv.w;
    ac[2][0] += a2 * wv.x; ac[2][1] += a2 * wv.y; ac[2][2] += a2 * wv.z; ac[2][3] += a2 * wv.w;
    ac[3][0] += a3 * wv.x; ac[3][1] += a3 * wv.y; ac[3][2] += a3 * wv.z; ac[3][3] += a3 * wv.w;
  }
#pragma unroll
  for (int i2 = 0; i2 < 4; ++i2) {
    float4 v = {ac[i2][0], ac[i2][1], ac[i2][2], ac[i2][3]};
    *(float4*)&y2[base + (size_t)(p0 + i2) * 64 + o0] = v;
  }
}

// ---------------- stage1e: in-place bn+relu over [M][64] ----------------
__global__ __launch_bounds__(256) void k_s1e(float* __restrict__ y2,
                                             const float* __restrict__ sc2, size_t ME4) {
  __shared__ float scs[128];
  int t = threadIdx.x;
  if (t < 128) scs[t] = sc2[t];
  __syncthreads();
  size_t stride = (size_t)gridDim.x * 256;
  for (size_t i = (size_t)blockIdx.x * 256 + t; i < ME4; i += stride) {
    float4 v = ((float4*)y2)[i];
    int c0 = (int)((i * 4) & 63);
    v.x = fmaxf(0.f, v.x * scs[c0 + 0] + scs[64 + c0 + 0]);
    v.y = fmaxf(0.f, v.y * scs[c0 + 1] + scs[64 + c0 + 1]);
    v.z = fmaxf(0.f, v.z * scs[c0 + 2] + scs[64 + c0 + 2]);
    v.w = fmaxf(0.f, v.w * scs[c0 + 3] + scs[64 + c0 + 3]);
    ((float4*)y2)[i] = v;
  }
}

// ---------------- FPS: LDS-resident coords, 1 barrier/iter ----------------
template <int N, int S, int PPT>
__global__ __launch_bounds__(N / PPT) void k_fps(const float* __restrict__ xyz,
                                                 int* __restrict__ fidx,
                                                 float* __restrict__ sxyz) {
  constexpr int T = N / PPT;
  constexpr int NW = T / 64;
  __shared__ float cl[N * 3];
  __shared__ float wv[2][NW];
  __shared__ int wi[2][NW];
  const int t = threadIdx.x;
  const int b = blockIdx.x;
  const float* base = xyz + (size_t)b * N * 3;
  for (int i = t; i < 3 * N; i += T) cl[i] = base[i];
  __syncthreads();
  float cx[PPT], cy[PPT], cz[PPT], dist[PPT];
#pragma unroll
  for (int j = 0; j < PPT; ++j) {
    int n = t + j * T;
    cx[j] = cl[n * 3 + 0];
    cy[j] = cl[n * 3 + 1];
    cz[j] = cl[n * 3 + 2];
    dist[j] = 1e10f;
  }
  float px = cl[0], py = cl[1], pz = cl[2];
  if (t == 0) {
    fidx[(size_t)b * S] = 0;
    sxyz[(size_t)b * S * 3 + 0] = px;
    sxyz[(size_t)b * S * 3 + 1] = py;
    sxyz[(size_t)b * S * 3 + 2] = pz;
  }
  int par = 0;
  for (int it = 1; it < S; ++it) {
    float bv = -1.0f;
    int bi = 0x7FFFFFFF;
#pragma unroll
    for (int j = 0; j < PPT; ++j) {
      float d = dist3(cx[j], cy[j], cz[j], px, py, pz);
      float dj = fminf(dist[j], d);
      dist[j] = dj;
      if (dj > bv) { bv = dj; bi = t + j * T; }  // j asc -> first (smallest n) in thread
    }
#pragma unroll
    for (int off = 32; off > 0; off >>= 1) {
      float ov = __shfl_xor(bv, off);
      int oi = __shfl_xor(bi, off);
      if (ov > bv || (ov == bv && oi < bi)) { bv = ov; bi = oi; }
    }
    if ((t & 63) == 0) { wv[par][t >> 6] = bv; wi[par][t >> 6] = bi; }
    __syncthreads();
    float v = wv[par][0];
    int ii = wi[par][0];
#pragma unroll
    for (int w = 1; w < NW; ++w) {
      float ov = wv[par][w];
      int oi = wi[par][w];
      if (ov > v || (ov == v && oi < ii)) { v = ov; ii = oi; }
    }
    px = cl[ii * 3 + 0]; py = cl[ii * 3 + 1]; pz = cl[ii * 3 + 2];
    if (t == 0) {
      fidx[(size_t)b * S + it] = ii;
      sxyz[((size_t)b * S + it) * 3 + 0] = px;
      sxyz[((size_t)b * S + it) * 3 + 1] = py;
      sxyz[((size_t)b * S + it) * 3 + 2] = pz;
    }
    par ^= 1;
  }
}

// ---------------- FPS single-wave variant (no barriers in the loop) ----------------
template <int N, int S, int PPT>
__global__ __launch_bounds__(64) void k_fpsw(const float* __restrict__ xyz,
                                             int* __restrict__ fidx,
                                             float* __restrict__ sxyz) {
  __shared__ float cl[N * 3];
  const int t = threadIdx.x;
  const int b = blockIdx.x;
  const float* base = xyz + (size_t)b * N * 3;
  for (int i = t; i < 3 * N; i += 64) cl[i] = base[i];
  __syncthreads();
  float cx[PPT], cy[PPT], cz[PPT], dist[PPT];
#pragma unroll
  for (int j = 0; j < PPT; ++j) {
    int n = t + j * 64;
    cx[j] = cl[n * 3 + 0];
    cy[j] = cl[n * 3 + 1];
    cz[j] = cl[n * 3 + 2];
    dist[j] = 1e10f;
  }
  float px = cl[0], py = cl[1], pz = cl[2];
  if (t == 0) {
    fidx[(size_t)b * S] = 0;
    sxyz[(size_t)b * S * 3 + 0] = px;
    sxyz[(size_t)b * S * 3 + 1] = py;
    sxyz[(size_t)b * S * 3 + 2] = pz;
  }
  for (int it = 1; it < S; ++it) {
    float bv = -1.0f;
    int bi = 0x7FFFFFFF;
#pragma unroll
    for (int j = 0; j < PPT; ++j) {
      float d = dist3(cx[j], cy[j], cz[j], px, py, pz);
      float dj = fminf(dist[j], d);
      dist[j] = dj;
      if (dj > bv) { bv = dj; bi = t + j * 64; }
    }
#pragma unroll
    for (int off = 32; off > 0; off >>= 1) {
      float ov = __shfl_xor(bv, off);
      int oi = __shfl_xor(bi, off);
      if (ov > bv || (ov == bv && oi < bi)) { bv = ov; bi = oi; }
    }
    px = cl[bi * 3 + 0]; py = cl[bi * 3 + 1]; pz = cl[bi * 3 + 2];
    if (t == 0) {
      fidx[(size_t)b * S + it] = bi;
      sxyz[((size_t)b * S + it) * 3 + 0] = px;
      sxyz[((size_t)b * S + it) * 3 + 1] = py;
      sxyz[((size_t)b * S + it) * 3 + 2] = pz;
    }
  }
}

// ---------------- KNN top-32: register candidates + incremental local min ----------
template <int NPT>
__global__ __launch_bounds__(256) void k_knn(const float* __restrict__ cxyz,
                                             const float* __restrict__ qxyz, int S,
                                             int* __restrict__ knn) {
  constexpr int N = NPT * 256;
  __shared__ float wv[2][4];
  __shared__ int wi[2][4];
  const int t = threadIdx.x;
  const int bs = blockIdx.x;
  const int b = bs / S;
  float qx = qxyz[(size_t)bs * 3 + 0];
  float qy = qxyz[(size_t)bs * 3 + 1];
  float qz = qxyz[(size_t)bs * 3 + 2];
  float qq = sumsq3(qx, qy, qz);
  const float* cb = cxyz + (size_t)b * N * 3;
  float ds[NPT];
  float lmin = 3.0e38f;
  int li = 0x7FFFFFFF;
#pragma unroll
  for (int j = 0; j < NPT; ++j) {
    int n = t + j * 256;
    float d = knndist(qx, qy, qz, qq, cb[(size_t)n * 3], cb[(size_t)n * 3 + 1],
                      cb[(size_t)n * 3 + 2]);
    ds[j] = d;
    if (d < lmin) { lmin = d; li = n; }
  }
  int par = 0;
  for (int r = 0; r < 32; ++r) {
    float bv = lmin;
    int bi = li;
#pragma unroll
    for (int off = 32; off > 0; off >>= 1) {
      float ov = __shfl_xor(bv, off);
      int oi = __shfl_xor(bi, off);
      if (ov < bv || (ov == bv && oi < bi)) { bv = ov; bi = oi; }
    }
    if ((t & 63) == 0) { wv[par][t >> 6] = bv; wi[par][t >> 6] = bi; }
    __syncthreads();
    float v = wv[par][0];
    int ii = wi[par][0];
#pragma unroll
    for (int w = 1; w < 4; ++w) {
      float ov = wv[par][w];
      int oi = wi[par][w];
      if (ov < v || (ov == v && oi < ii)) { v = ov; ii = oi; }
    }
    if (t == 0) knn[(size_t)bs * 32 + r] = ii;
    if (li == ii) {  // only the owner rescans
#pragma unroll
      for (int j = 0; j < NPT; ++j)
        if (t + j * 256 == ii) ds[j] = 3.0e38f;
      lmin = 3.0e38f;
      li = 0x7FFFFFFF;
#pragma unroll
      for (int j = 0; j < NPT; ++j)
        if (ds[j] < lmin) { lmin = ds[j]; li = t + j * 256; }
    }
    par ^= 1;
  }
}

// ---------------- shared helpers for SG GEMMs ----------------
#define KP 36  // padded row length (floats) for K=32 tiles: breaks bank-wrap
__device__ __forceinline__ int swzcol(int d, int k) {
  return (k & 3) | ((((unsigned(k) >> 2) ^ (unsigned(d) >> 2)) & 7) << 2);
}

// gather raw neighbor features V (D rows) into swizzled LDS, float4 granularity
template <int D, int NT>
__device__ __forceinline__ void sg_gatherV(const float* __restrict__ f, int Nf, int b,
                                           const int* __restrict__ nidx,
                                           float* __restrict__ V, int t) {
  constexpr int K = 32, DQ = D / 4;
  const float4* f4 = (const float4*)f;
  for (int idx = t; idx < K * DQ; idx += NT) {
    int k = idx / DQ, dq = idx - k * DQ;
    float4 v = f4[((size_t)b * Nf + nidx[k]) * DQ + dq];
    int d0 = dq * 4;
    V[(d0 + 0) * KP + swzcol(d0 + 0, k)] = v.x;
    V[(d0 + 1) * KP + swzcol(d0 + 1, k)] = v.y;
    V[(d0 + 2) * KP + swzcol(d0 + 2, k)] = v.z;
    V[(d0 + 3) * KP + swzcol(d0 + 3, k)] = v.w;
  }
}

// 8x4 register tile, contraction split across 2 thread-groups, prefetched staging.
// X: [>=DR][KP] swizzled LDS; WT: [DR][O] global; wch: [CH][O] floats LDS.
// Thread: tid2 = t&(NT/2-1), g = t/(NT/2); o0 = (tid2>>3)*8, kq = tid2&7.
// Accumulates rows [g*DR/2,(g+1)*DR/2) into ac (caller zero-inits & combines).
template <int DR, int O, int NT, int CH>
__device__ __forceinline__ void sg_gemm8(const float* __restrict__ X,
                                         const float* __restrict__ WT,
                                         float* __restrict__ wch, int t, int o0,
                                         int kq, int g, float (&ac)[8][4]) {
  constexpr int HR = DR / 2, HC = CH / 2, NCH = DR / CH;
  constexpr int PF = (CH * O) / (NT * 4);
  float4 pf[PF];
#pragma unroll
  for (int q = 0; q < PF; ++q) {
    int fidx = (t + q * NT) * 4;
    int r = fidx / O, cc = fidx - r * O;
    int gr = (r < HC) ? r : (HR - HC + r);
    pf[q] = *(const float4*)&WT[(size_t)gr * O + cc];
  }
  const int dbase0 = g * HR, wbase = g * HC;
  for (int c = 0; c < NCH; ++c) {
    __syncthreads();
#pragma unroll
    for (int q = 0; q < PF; ++q) *(float4*)&wch[(t + q * NT) * 4] = pf[q];
    __syncthreads();
    if (c + 1 < NCH) {
#pragma unroll
      for (int q = 0; q < PF; ++q) {
        int fidx = (t + q * NT) * 4;
        int r = fidx / O, cc = fidx - r * O;
        int gr = (r < HC) ? ((c + 1) * HC + r) : (HR + (c + 1) * HC + (r - HC));
        pf[q] = *(const float4*)&WT[(size_t)gr * O + cc];
      }
    }
    const int dbase = dbase0 + c * HC;
#pragma unroll
    for (int dd = 0; dd < HC; ++dd) {
      int d = dbase + dd;
      const float4 av = *(const float4*)&X[d * KP + ((kq ^ ((d >> 2) & 7)) << 2)];
      const float4 w0 = *(const float4*)&wch[(wbase + dd) * O + o0];
      const float4 w1 = *(const float4*)&wch[(wbase + dd) * O + o0 + 4];
      ac[0][0] += w0.x*av.x; ac[0][1] += w0.x*av.y; ac[0][2] += w0.x*av.z; ac[0][3] += w0.x*av.w;
      ac[1][0] += w0.y*av.x; ac[1][1] += w0.y*av.y; ac[1][2] += w0.y*av.z; ac[1][3] += w0.y*av.w;
      ac[2][0] += w0.z*av.x; ac[2][1] += w0.z*av.y; ac[2][2] += w0.z*av.z; ac[2][3] += w0.z*av.w;
      ac[3][0] += w0.w*av.x; ac[3][1] += w0.w*av.y; ac[3][2] += w0.w*av.z; ac[3][3] += w0.w*av.w;
      ac[4][0] += w1.x*av.x; ac[4][1] += w1.x*av.y; ac[4][2] += w1.x*av.z; ac[4][3] += w1.x*av.w;
      ac[5][0] += w1.y*av.x; ac[5][1] += w1.y*av.y; ac[5][2] += w1.y*av.z; ac[5][3] += w1.y*av.w;
      ac[6][0] += w1.z*av.x; ac[6][1] += w1.z*av.y; ac[6][2] += w1.z*av.z; ac[6][3] += w1.z*av.w;
      ac[7][0] += w1.w*av.x; ac[7][1] += w1.w*av.y; ac[7][2] += w1.w*av.z; ac[7][3] += w1.w*av.w;
    }
  }
}

// combine split-contraction partials: group1 -> LDS (wch), group0 adds. 2 rounds of
// 4 rows so wch only needs 4*(NT/2)*4 floats. Layout [4][NH][4]: conflict-free.
template <int NT>
__device__ __forceinline__ void sg_combine(float* __restrict__ wch, int tid2, int g,
                                           float (&ac)[8][4]) {
  constexpr int NH = NT / 2;
#pragma unroll
  for (int h = 0; h < 2; ++h) {
    __syncthreads();
    if (g == 1) {
#pragma unroll
      for (int i = 0; i < 4; ++i)
        *(float4*)&wch[(i * NH + tid2) * 4] = *(float4*)&ac[h * 4 + i][0];
    }
    __syncthreads();
    if (g == 0) {
#pragma unroll
      for (int i = 0; i < 4; ++i) {
        float4 v = *(const float4*)&wch[(i * NH + tid2) * 4];
        ac[h*4+i][0] += v.x; ac[h*4+i][1] += v.y; ac[h*4+i][2] += v.z; ac[h*4+i][3] += v.w;
      }
    }
  }
}

// correction c[i] = sum_d WdT[d][o0+i] * q[d] (8 outputs), reduced over kq-groups
template <int D, int O>
__device__ __forceinline__ void sg_corr8(const float* __restrict__ WdT,
                                         const float* __restrict__ fqs, int o0, int kq,
                                         float (&c)[8]) {
#pragma unroll
  for (int i = 0; i < 8; ++i) c[i] = 0.f;
  for (int d = kq * (D / 8); d < (kq + 1) * (D / 8); ++d) {
    float qv = fqs[d];
    float4 w0 = *(const float4*)&WdT[(size_t)d * O + o0];
    float4 w1 = *(const float4*)&WdT[(size_t)d * O + o0 + 4];
    c[0] += w0.x * qv; c[1] += w0.y * qv; c[2] += w0.z * qv; c[3] += w0.w * qv;
    c[4] += w1.x * qv; c[5] += w1.y * qv; c[6] += w1.z * qv; c[7] += w1.w * qv;
  }
#pragma unroll
  for (int m = 1; m < 8; m <<= 1) {
#pragma unroll
    for (int i = 0; i < 8; ++i) c[i] += __shfl_xor(c[i], m);
  }
}

// ---------------- pass A: gather + split GEMM A -> statsA only ----------------
template <int D, int NT, int CH>
__global__ __launch_bounds__(NT) void k_sgA(const float* __restrict__ f, int Nf, int S,
                                            const int* __restrict__ fpsidx,
                                            const int* __restrict__ knn,
                                            const float* __restrict__ waT,
                                            const float* __restrict__ WdT,
                                            float* __restrict__ statsOut) {
  constexpr int D2 = 2 * D, O = D2, K = 32, DQ = D / 4;
  __shared__ __align__(16) float V[D * KP];
  __shared__ __align__(16) float wch[CH * O];
  __shared__ __align__(16) float fqs[D];
  __shared__ int nidx[K];
  __shared__ float red[2 * O];
  const int t = threadIdx.x;
  const int bs = blockIdx.x;
  const int b = bs / S;
  const int qi = fpsidx[bs];
  if (t < K) nidx[t] = knn[(size_t)bs * K + t];
  const float4* f4 = (const float4*)f;
  for (int i = t; i < DQ; i += NT)
    ((float4*)fqs)[i] = f4[((size_t)b * Nf + qi) * DQ + i];
  __syncthreads();
  sg_gatherV<D, NT>(f, Nf, b, nidx, V, t);
  const int tid2 = t & (NT / 2 - 1);
  const int g = t >= (NT / 2);
  const int kq = tid2 & 7;
  const int o0 = (tid2 >> 3) * 8;
  float ac[8][4];
#pragma unroll
  for (int i = 0; i < 8; ++i)
#pragma unroll
    for (int j = 0; j < 4; ++j) ac[i][j] = 0.f;
  sg_gemm8<D, O, NT, CH>(V, waT, wch, t, o0, kq, g, ac);  // 1st barrier covers gather
  sg_combine<NT>(wch, tid2, g, ac);
  if (g == 0) {
    float c8[8];
    sg_corr8<D, O>(WdT, fqs, o0, kq, c8);
#pragma unroll
    for (int i = 0; i < 8; ++i) {
      float a0 = ac[i][0] + c8[i], a1 = ac[i][1] + c8[i];
      float a2 = ac[i][2] + c8[i], a3 = ac[i][3] + c8[i];
      float sv = a0 + a1 + a2 + a3;
      float sq = a0 * a0 + a1 * a1 + a2 * a2 + a3 * a3;
#pragma unroll
      for (int m = 1; m < 8; m <<= 1) {
        sv += __shfl_xor(sv, m);
        sq += __shfl_xor(sq, m);
      }
      if (kq == 0) {
        red[o0 + i] = sv;
        red[O + o0 + i] = sq;
      }
    }
  }
  __syncthreads();
  float* slot = statsOut + (size_t)(bs & 255) * (2 * O);
  for (int i = t; i < 2 * O; i += NT) atomicAdd(&slot[i], red[i]);
}

// ------- pass AB: split A recompute, bnA+relu, GEMM B -> statsB + max/min yB -------
template <int D, int NT, int CH>
__global__ __launch_bounds__(NT) void k_sgAB(const float* __restrict__ f, int Nf, int S,
                                             const int* __restrict__ fpsidx,
                                             const int* __restrict__ knn,
                                             const float* __restrict__ waT,
                                             const float* __restrict__ WdT,
                                             const float* __restrict__ wbT,
                                             const float* __restrict__ bnA,
                                             float* __restrict__ statsOut,
                                             float* __restrict__ mm) {
  constexpr int D2 = 2 * D, O = D2, K = 32, DQ = D / 4;
  __shared__ __align__(16) float VZ[O * KP];  // V rows [0,D) then reused as zb [0,O)
  __shared__ __align__(16) float wch[CH * O];
  __shared__ __align__(16) float fqs[D];
  __shared__ int nidx[K];
  __shared__ float red[2 * O];
  __shared__ float scb[2 * O];
  const int t = threadIdx.x;
  const int bs = blockIdx.x;
  const int b = bs / S;
  const int qi = fpsidx[bs];
  if (t < K) nidx[t] = knn[(size_t)bs * K + t];
  const float4* f4 = (const float4*)f;
  for (int i = t; i < DQ; i += NT)
    ((float4*)fqs)[i] = f4[((size_t)b * Nf + qi) * DQ + i];
  for (int i = t; i < 2 * O; i += NT) scb[i] = bnA[i];
  __syncthreads();
  sg_gatherV<D, NT>(f, Nf, b, nidx, VZ, t);
  const int tid2 = t & (NT / 2 - 1);
  const int g = t >= (NT / 2);
  const int kq = tid2 & 7;
  const int o0 = (tid2 >> 3) * 8;
  float ac[8][4];
#pragma unroll
  for (int i = 0; i < 8; ++i)
#pragma unroll
    for (int j = 0; j < 4; ++j) ac[i][j] = 0.f;
  sg_gemm8<D, O, NT, CH>(VZ, waT, wch, t, o0, kq, g, ac);
  sg_combine<NT>(wch, tid2, g, ac);
  // zA = relu(bnA(yA + corr)) written by group0 only (covers all O x K slots)
  if (g == 0) {
    float c8[8];
    sg_corr8<D, O>(WdT, fqs, o0, kq, c8);
#pragma unroll
    for (int i = 0; i < 8; ++i) {
      int o = o0 + i;
      float sA = scb[o], tA = scb[O + o];
      float4 z;
      z.x = fmaxf(0.f, (ac[i][0] + c8[i]) * sA + tA);
      z.y = fmaxf(0.f, (ac[i][1] + c8[i]) * sA + tA);
      z.z = fmaxf(0.f, (ac[i][2] + c8[i]) * sA + tA);
      z.w = fmaxf(0.f, (ac[i][3] + c8[i]) * sA + tA);
      *(float4*)&VZ[o * KP + ((kq ^ ((o >> 2) & 7)) << 2)] = z;
    }
  }
  float ac2[8][4];
#pragma unroll
  for (int i = 0; i < 8; ++i)
#pragma unroll
    for (int j = 0; j < 4; ++j) ac2[i][j] = 0.f;
  sg_gemm8<O, O, NT, CH>(VZ, wbT, wch, t, o0, kq, g, ac2);  // 1st barrier covers zA
  sg_combine<NT>(wch, tid2, g, ac2);
  float* mrow = mm + (size_t)bs * 2 * O;
  if (g == 0) {
#pragma unroll
    for (int i = 0; i < 8; ++i) {
      float a0 = ac2[i][0], a1 = ac2[i][1], a2 = ac2[i][2], a3 = ac2[i][3];
      float sv = a0 + a1 + a2 + a3;
      float sq = a0 * a0 + a1 * a1 + a2 * a2 + a3 * a3;
      float mx = fmaxf(fmaxf(a0, a1), fmaxf(a2, a3));
      float mn = fminf(fminf(a0, a1), fminf(a2, a3));
#pragma unroll
      for (int m = 1; m < 8; m <<= 1) {
        sv += __shfl_xor(sv, m);
        sq += __shfl_xor(sq, m);
        mx = fmaxf(mx, __shfl_xor(mx, m));
        mn = fminf(mn, __shfl_xor(mn, m));
      }
      if (kq == 0) {
        red[o0 + i] = sv;
        red[O + o0 + i] = sq;
        mrow[o0 + i] = mx;
        mrow[O + o0 + i] = mn;
      }
    }
  }
  __syncthreads();
  float* slot = statsOut + (size_t)(bs & 255) * (2 * O);
  for (int i = t; i < 2 * O; i += NT) atomicAdd(&slot[i], red[i]);
}

// ------- finalize: out = relu(sB * (sB>=0 ? maxYB : minYB) + tB) ------------------
template <int O>
__global__ __launch_bounds__(256) void k_fin(const float* __restrict__ mm,
                                             const float* __restrict__ bnB, int S,
                                             float* __restrict__ out, int finalOut) {
  int idx = blockIdx.x * 256 + threadIdx.x;
  int o, bs;
  if (finalOut) {
    int s = idx % S;
    int bo = idx / S;
    o = bo % O;
    int b = bo / O;
    bs = b * S + s;
  } else {
    o = idx % O;
    bs = idx / O;
  }
  float sB = bnB[o], tB = bnB[O + o];
  const float* r = mm + (size_t)bs * 2 * O;
  float ext = (sB >= 0.f) ? r[o] : r[O + o];
  out[idx] = fmaxf(0.f, sB * ext + tB);
}

// ---------------- host launch ----------------
extern "C" void kernel_launch(void* const* d_in, const int* in_sizes, int n_in,
                              void* d_out, int out_size, void* d_ws, size_t ws_size,
                              hipStream_t stream) {
  (void)in_sizes; (void)n_in; (void)out_size; (void)ws_size;
  const float* x    = (const float*)d_in[0];
  const float* w1   = (const float*)d_in[1];
  const float* g1   = (const float*)d_in[2];
  const float* b1   = (const float*)d_in[3];
  const float* w2   = (const float*)d_in[4];
  const float* g2   = (const float*)d_in[5];
  const float* b2   = (const float*)d_in[6];
  const float* s1wa = (const float*)d_in[7];
  const float* s1ga = (const float*)d_in[8];
  const float* s1ba = (const float*)d_in[9];
  const float* s1wb = (const float*)d_in[10];
  const float* s1gb = (const float*)d_in[11];
  const float* s1bb = (const float*)d_in[12];
  const float* s2wa = (const float*)d_in[13];
  const float* s2ga = (const float*)d_in[14];
  const float* s2ba = (const float*)d_in[15];
  const float* s2wb = (const float*)d_in[16];
  const float* s2gb = (const float*)d_in[17];
  const float* s2bb = (const float*)d_in[18];
  float* out = (float*)d_out;

  char* wsp = (char*)d_ws;
  size_t off = 0;
  auto alloc = [&](size_t floats) {
    void* p = wsp + off;
    off += ((floats * 4 + 255) & ~(size_t)255);
    return p;
  };
  float* xyz  = (float*)alloc(786432);     // [B][N][3]
  float* y1   = (float*)alloc(16777216);   // [B*N][64] conv1 raw -> conv2 in-place
  float* y2f  = y1;                        // alias (k_s1c tile-in-LDS then overwrite: safe)
  float* f1f  = (float*)alloc(2097152);    // [B][S1][128]
  float* xyz1 = (float*)alloc(49152);      // [B][S1][3]
  float* xyz2 = (float*)alloc(24576);      // [B][S2][3]
  int* fi1    = (int*)alloc(16384);        // [B][S1]
  int* fi2    = (int*)alloc(8192);         // [B][S2]
  int* kn1    = (int*)alloc(524288);       // [B][S1][32]
  int* kn2    = (int*)alloc(262144);       // [B][S2][32]
  float* w2T  = (float*)alloc(4096);
  float* waT1 = (float*)alloc(16384);
  float* wbT1 = (float*)alloc(16384);
  float* waT2 = (float*)alloc(65536);
  float* wbT2 = (float*)alloc(65536);
  float* WdT1 = (float*)alloc(8192);       // [64][128]
  float* WdT2 = (float*)alloc(32768);      // [128][256]
  float* stats = (float*)alloc(411392);
  float* part_s1 = stats;                  // [64][128]
  float* part_s2 = stats + 8192;           // [64][128]
  float* partA1  = stats + 16384;          // [256][256]
  float* partB1  = stats + 81920;          // [256][256]
  float* partA2  = stats + 147456;         // [256][512]
  float* partB2  = stats + 278528;         // [256][512]
  float* sc1  = stats + 409600;            // [2*64]
  float* sc2  = sc1 + 128;
  float* bnA1 = sc2 + 128;                 // [2*128]
  float* bnB1 = bnA1 + 256;
  float* bnA2 = bnB1 + 256;                // [2*256]
  float* bnB2 = bnA2 + 512;
  // per-(bs,o) max/min of yB: max(16384*256, 8192*512) = 4,194,304 floats (16 MB)
  float* mm = (float*)alloc(4194304);

  hipMemsetAsync(stats, 0, (size_t)409600 * 4, stream);

  // weight transposes + split-correction weights
  k_transpose<<<(64 * 64 + 255) / 256, 256, 0, stream>>>(w2, w2T, 64, 64);
  k_transpose<<<(128 * 128 + 255) / 256, 256, 0, stream>>>(s1wa, waT1, 128, 128);
  k_transpose<<<(128 * 128 + 255) / 256, 256, 0, stream>>>(s1wb, wbT1, 128, 128);
  k_transpose<<<(256 * 256 + 255) / 256, 256, 0, stream>>>(s2wa, waT2, 256, 256);
  k_transpose<<<(256 * 256 + 255) / 256, 256, 0, stream>>>(s2wb, wbT2, 256, 256);
  k_wdiff<<<(64 * 128 + 255) / 256, 256, 0, stream>>>(s1wa, WdT1, 128, 64);
  k_wdiff<<<(128 * 256 + 255) / 256, 256, 0, stream>>>(s2wa, WdT2, 256, 128);

  const size_t MN = (size_t)NB * NP;  // 262144
  // stage 1
  k_s1a<<<(int)(MN / 256), 256, 0, stream>>>(x, w1, xyz, y1);
  k_colstats<<<1024, 256, 0, stream>>>(y1, MN * 16, part_s1);
  k_bnfinal<<<1, 64, 0, stream>>>(part_s1, g1, b1, 1.f / (float)MN, 64, 64, sc1);
  k_s1c<<<(int)(MN / 64), 256, 0, stream>>>(y1, w2T, sc1, y2f);
  k_colstats<<<1024, 256, 0, stream>>>(y2f, MN * 16, part_s2);
  k_bnfinal<<<1, 64, 0, stream>>>(part_s2, g2, b2, 1.f / (float)MN, 64, 64, sc2);
  k_s1e<<<2048, 256, 0, stream>>>(y2f, sc2, MN * 16);

  // sampling/grouping indices
  k_fps<NP, 512, 32><<<NB, 256, 0, stream>>>(xyz, fi1, xyz1);
  k_knn<32><<<NB * 512, 256, 0, stream>>>(xyz, xyz1, 512, kn1);

  const float icA1 = 1.f / (32.f * 512.f * 32.f);
  const float icA2 = 1.f / (32.f * 256.f * 32.f);

  // ---- SG block 1: A(stats) -> AB(stats+minmax) -> finalize ----
  k_sgA<64, 256, 16><<<NB * 512, 256, 0, stream>>>(y2f, NP, 512, fi1, kn1, waT1, WdT1,
                                                   partA1);
  k_bnfinal<<<1, 128, 0, stream>>>(partA1, s1ga, s1ba, icA1, 128, 256, bnA1);
  k_sgAB<64, 256, 32><<<NB * 512, 256, 0, stream>>>(y2f, NP, 512, fi1, kn1, waT1, WdT1,
                                                    wbT1, bnA1, partB1, mm);
  k_bnfinal<<<1, 128, 0, stream>>>(partB1, s1gb, s1bb, icA1, 128, 256, bnB1);
  k_fin<128><<<8192, 256, 0, stream>>>(mm, bnB1, 512, f1f, 0);

  k_fpsw<512, 256, 8><<<NB, 64, 0, stream>>>(xyz1, fi2, xyz2);
  k_knn<2><<<NB * 256, 256, 0, stream>>>(xyz1, xyz2, 256, kn2);

  // ---- SG block 2 ----
  k_sgA<128, 512, 16><<<NB * 256, 512, 0, stream>>>(f1f, 512, 256, fi2, kn2, waT2, WdT2,
                                                    partA2);
  k_bnfinal<<<1, 256, 0, stream>>>(partA2, s2ga, s2ba, icA2, 256, 256, bnA2);
  k_sgAB<128, 512, 32><<<NB * 256, 512, 0, stream>>>(f1f, 512, 256, fi2, kn2, waT2, WdT2,
                                                     wbT2, bnA2, partB2, mm);
  k_bnfinal<<<1, 256, 0, stream>>>(partB2, s2gb, s2bb, icA2, 256, 256, bnB2);
  k_fin<256><<<8192, 256, 0, stream>>>(mm, bnB2, 256, out, 1);
}